// Round 10
// baseline (5676.607 us; speedup 1.0000x reference)
//
#include <hip/hip_runtime.h>
#include <math.h>

#define B_SZ 4096
#define T_SZ 80
#define V_SZ 80
#define E_SZ 8
#define H_SZ 256
#define G4   1024   // 4*H
#define RB   32     // rows per persistent block
#define NBLK (B_SZ / RB)   // 128 blocks

typedef __attribute__((ext_vector_type(8))) short short8;
typedef __attribute__((ext_vector_type(4))) float f32x4;

__device__ __forceinline__ float sigm(float x) {
    return 1.f / (1.f + __expf(-x));
}
__device__ __forceinline__ float tanhfast(float x) {
    x = fminf(fmaxf(x, -15.f), 15.f);
    float t = __expf(-2.f * x);
    return (1.f - t) / (1.f + t);
}
__device__ __forceinline__ ushort f2bf(float f) {   // RNE f32->bf16
    unsigned u = __float_as_uint(f);
    u = (u + 0x7fffu + ((u >> 16) & 1u)) >> 16;
    return (ushort)u;
}
__device__ __forceinline__ f32x4 mfma16(short8 a, short8 b, f32x4 c) {
    return __builtin_amdgcn_mfma_f32_16x16x32_bf16(a, b, c, 0, 0, 0);
}

// G1[v][col] = b1[col] + sum_e emb[v][e] * W1[e][col]
__global__ __launch_bounds__(256) void g1_kernel(const float* __restrict__ emb,
                                                 const float* __restrict__ W1,
                                                 const float* __restrict__ b1,
                                                 float* __restrict__ G1) {
    int idx = blockIdx.x * 256 + threadIdx.x;
    if (idx >= V_SZ * G4) return;
    int v = idx >> 10, col = idx & 1023;
    float g = b1[col];
#pragma unroll
    for (int e = 0; e < E_SZ; e++)
        g += emb[v * E_SZ + e] * W1[e * G4 + col];
    G1[idx] = g;
}

// Fragment-ordered weights for the row-local kernel.
// flat idx = ((w*KT + kt)*8 + cf)*512 + l*8 + j
//   k   = k0 + kt*32 + (l>>4)*8 + j
//   col = (cf>>1)*256 + w*32 + (cf&1)*16 + (l&15)     (gate = cf>>1, hcol-half = cf&1)
__global__ __launch_bounds__(256) void wtransf2(const float* __restrict__ src, int k0,
                                                int KTmask, int KTsh,
                                                ushort* __restrict__ out) {
    int idx = blockIdx.x * 256 + threadIdx.x;
    int j  = idx & 7;
    int l  = (idx >> 3) & 63;
    int cf = (idx >> 9) & 7;
    int kt = (idx >> 12) & KTmask;
    int w  = idx >> (12 + KTsh);
    int k  = k0 + kt * 32 + (l >> 4) * 8 + j;
    int col = (cf >> 1) * 256 + w * 32 + (cf & 1) * 16 + (l & 15);
    out[idx] = f2bf(src[(size_t)k * G4 + col]);
}

// WdT[v][h] = bf16(Wd[h*V + v])
__global__ __launch_bounds__(256) void wdtrans(const float* __restrict__ src,
                                               ushort* __restrict__ out) {
    int idx = blockIdx.x * 256 + threadIdx.x;
    if (idx >= V_SZ * H_SZ) return;
    int v = idx >> 8, h = idx & 255;
    out[idx] = f2bf(src[h * V_SZ + v]);
}

// ---------------------------------------------------------------------------
// Persistent row-local 2-layer LSTM. 128 blocks x 512 threads; block owns 32
// batch rows for ALL 80 timesteps. No inter-block communication of any kind:
// h1/h2 ping-pong in LDS (canonical MFMA A-fragment layout), c in registers,
// W streamed L2->VGPR (read exactly once per block per step).
//
// Canonical A-frag LDS layout for element (row, k), row in [0,32), k in [0,256):
//   I(row,k) = ((row>>4)*8 + (k>>5))*512 + ((row&15) + ((k>>3)&3)*16)*8 + (k&7)
// GEMM read: frag (rt,kt): lds[(rt*8+kt)*512 + l*8 + j] == A[rt*16+(l&15)][kt*32+(l>>4)*8+j]  ✓
// Epilogue write of cell (row = rt*16+l4*4+r, hc = w*32+hh*16+l15):
//   (hc>>5)==w, ((hc>>3)&3)==hh*2+(l15>>3), (hc&7)==l15&7  → static index.
// ---------------------------------------------------------------------------
__global__ __launch_bounds__(512) void lstm_rowlocal(
    const int*   __restrict__ feat,
    const float* __restrict__ G1,
    const float* __restrict__ b2,
    const ushort* __restrict__ W1f,
    const ushort* __restrict__ W2f,
    ushort* __restrict__ h2g,
    int padsel) {

    __shared__ __align__(16) ushort h1s[2][8192];   // 2 x 16 KB
    __shared__ __align__(16) ushort h2s[2][8192];   // 2 x 16 KB
    __shared__ ushort pad[12288];                   // 24 KB -> 88 KB total: 1 block/CU

    const int tid = threadIdx.x;
    const int w = tid >> 6, l = tid & 63;
    const int l15 = l & 15, l4 = l >> 4;
    const int m0 = blockIdx.x * RB;

    if (padsel) {                       // never true at runtime; keeps pad live
        pad[tid] = (ushort)tid;
        h2g[tid] = pad[tid ^ 1];
    }

    // hoisted b2 for this lane's 8 gate-col fragments
    float bb[8];
#pragma unroll
    for (int cf = 0; cf < 8; cf++)
        bb[cf] = b2[(cf >> 1) * 256 + w * 32 + (cf & 1) * 16 + l15];

    float c1r[16], c2r[16];             // cell idx = (rt*4+r)*2 + hh
#pragma unroll
    for (int i = 0; i < 16; i++) { c1r[i] = 0.f; c2r[i] = 0.f; }

    const ushort* w1p = W1f + (size_t)(w * 8) * 8 * 512 + l * 8;    // per (wave,kt): 8 frags x 512
    const ushort* w2p = W2f + (size_t)(w * 16) * 8 * 512 + l * 8;

    const int hwrB = (l15 >> 3);        // h-write lane-part
    const f32x4 zero4 = {0.f, 0.f, 0.f, 0.f};

#pragma unroll 1
    for (int t = 0; t < T_SZ; t++) {
        // ================= phase A: layer 1 (K = 256, h1(t-1)) =================
        f32x4 acc[2][8];
#pragma unroll
        for (int rt = 0; rt < 2; rt++)
#pragma unroll
            for (int cf = 0; cf < 8; cf++) acc[rt][cf] = zero4;

        if (t > 0) {
            const ushort* ab = h1s[(t + 1) & 1];    // h1(t-1)
            short8 wf[2][8];
#pragma unroll
            for (int cf = 0; cf < 8; cf++)
                wf[0][cf] = *(const short8*)(w1p + (size_t)cf * 512);
#pragma unroll
            for (int kt = 0; kt < 8; kt++) {
                if (kt < 7) {
#pragma unroll
                    for (int cf = 0; cf < 8; cf++)
                        wf[(kt + 1) & 1][cf] =
                            *(const short8*)(w1p + ((size_t)(kt + 1) * 8 + cf) * 512);
                }
                short8 a0 = *(const short8*)(ab + (0 * 8 + kt) * 512 + l * 8);
                short8 a1 = *(const short8*)(ab + (1 * 8 + kt) * 512 + l * 8);
                __builtin_amdgcn_s_setprio(1);
#pragma unroll
                for (int cf = 0; cf < 8; cf++) {
                    acc[0][cf] = mfma16(a0, wf[kt & 1][cf], acc[0][cf]);
                    acc[1][cf] = mfma16(a1, wf[kt & 1][cf], acc[1][cf]);
                }
                __builtin_amdgcn_s_setprio(0);
            }
        }

        {   // epilogue L1 -> h1s[t&1]
            ushort* ho = h1s[t & 1];
#pragma unroll
            for (int rt = 0; rt < 2; rt++) {
#pragma unroll
                for (int r = 0; r < 4; r++) {
                    const int row = rt * 16 + l4 * 4 + r;
                    const int fr = feat[(size_t)(m0 + row) * T_SZ + t];
                    const float* gr = G1 + (size_t)fr * G4;
#pragma unroll
                    for (int hh = 0; hh < 2; hh++) {
                        const int hc = w * 32 + hh * 16 + l15;
                        float gi = acc[rt][0 + hh][r] + gr[hc];
                        float gj = acc[rt][2 + hh][r] + gr[256 + hc];
                        float gf = acc[rt][4 + hh][r] + gr[512 + hc];
                        float go = acc[rt][6 + hh][r] + gr[768 + hc];
                        const int ci = (rt * 4 + r) * 2 + hh;
                        float cp = t ? c1r[ci] : 0.f;
                        float cn = cp * sigm(gf + 1.f) + sigm(gi) * tanhfast(gj);
                        float hn = tanhfast(cn) * sigm(go);
                        c1r[ci] = cn;
                        ho[(rt * 8 + w) * 512 +
                           ((row & 15) + (hh * 2 + hwrB) * 16) * 8 + (l15 & 7)] = f2bf(hn);
                    }
                }
            }
        }
        __syncthreads();

        // ============ phase B: layer 2 (K = 512: h1(t) ++ h2(t-1)) ============
#pragma unroll
        for (int rt = 0; rt < 2; rt++)
#pragma unroll
            for (int cf = 0; cf < 8; cf++) acc[rt][cf] = zero4;

        {
            const ushort* a1b = h1s[t & 1];         // h1(t):   k 0..255
            const ushort* a2b = h2s[(t + 1) & 1];   // h2(t-1): k 256..511
            short8 wf[2][8];
#pragma unroll
            for (int cf = 0; cf < 8; cf++)
                wf[0][cf] = *(const short8*)(w2p + (size_t)cf * 512);
#pragma unroll
            for (int kt = 0; kt < 8; kt++) {
                // prefetch next kt (kt+1 <= 8; kt=8 frags exist in W2f always)
#pragma unroll
                for (int cf = 0; cf < 8; cf++)
                    wf[(kt + 1) & 1][cf] =
                        *(const short8*)(w2p + ((size_t)(kt + 1) * 8 + cf) * 512);
                short8 a0 = *(const short8*)(a1b + (0 * 8 + kt) * 512 + l * 8);
                short8 a1 = *(const short8*)(a1b + (1 * 8 + kt) * 512 + l * 8);
                __builtin_amdgcn_s_setprio(1);
#pragma unroll
                for (int cf = 0; cf < 8; cf++) {
                    acc[0][cf] = mfma16(a0, wf[kt & 1][cf], acc[0][cf]);
                    acc[1][cf] = mfma16(a1, wf[kt & 1][cf], acc[1][cf]);
                }
                __builtin_amdgcn_s_setprio(0);
            }
            if (t > 0) {
#pragma unroll
                for (int kt = 8; kt < 16; kt++) {
                    if (kt < 15) {
#pragma unroll
                        for (int cf = 0; cf < 8; cf++)
                            wf[(kt + 1) & 1][cf] =
                                *(const short8*)(w2p + ((size_t)(kt + 1) * 8 + cf) * 512);
                    }
                    short8 a0 = *(const short8*)(a2b + (0 * 8 + kt - 8) * 512 + l * 8);
                    short8 a1 = *(const short8*)(a2b + (1 * 8 + kt - 8) * 512 + l * 8);
                    __builtin_amdgcn_s_setprio(1);
#pragma unroll
                    for (int cf = 0; cf < 8; cf++) {
                        acc[0][cf] = mfma16(a0, wf[kt & 1][cf], acc[0][cf]);
                        acc[1][cf] = mfma16(a1, wf[kt & 1][cf], acc[1][cf]);
                    }
                    __builtin_amdgcn_s_setprio(0);
                }
            }
        }

        {   // epilogue L2 -> h2s[t&1]; at t=79 also emit h2 row-major to global
            ushort* ho = h2s[t & 1];
#pragma unroll
            for (int rt = 0; rt < 2; rt++) {
#pragma unroll
                for (int r = 0; r < 4; r++) {
                    const int row = rt * 16 + l4 * 4 + r;
#pragma unroll
                    for (int hh = 0; hh < 2; hh++) {
                        const int hc = w * 32 + hh * 16 + l15;
                        float gi = acc[rt][0 + hh][r] + bb[0 + hh];
                        float gj = acc[rt][2 + hh][r] + bb[2 + hh];
                        float gf = acc[rt][4 + hh][r] + bb[4 + hh];
                        float go = acc[rt][6 + hh][r] + bb[6 + hh];
                        const int ci = (rt * 4 + r) * 2 + hh;
                        float cp = t ? c2r[ci] : 0.f;
                        float cn = cp * sigm(gf + 1.f) + sigm(gi) * tanhfast(gj);
                        float hn = tanhfast(cn) * sigm(go);
                        c2r[ci] = cn;
                        ushort hb = f2bf(hn);
                        ho[(rt * 8 + w) * 512 +
                           ((row & 15) + (hh * 2 + hwrB) * 16) * 8 + (l15 & 7)] = hb;
                        if (t == T_SZ - 1)
                            h2g[(size_t)(m0 + row) * H_SZ + hc] = hb;
                    }
                }
            }
        }
        __syncthreads();
    }
}

// dense+loss via MFMA: wave computes 16 rows x 80 v-cols; shfl softmax.
__global__ __launch_bounds__(256) void dense_loss(const ushort* __restrict__ h2,
                                                  const ushort* __restrict__ WdT,
                                                  const float* __restrict__ bd,
                                                  const int* __restrict__ labels,
                                                  float* __restrict__ out) {
    const int tid = threadIdx.x;
    const int w = tid >> 6, l = tid & 63;
    const int l15 = l & 15, l4 = l >> 4;
    const int m0 = blockIdx.x * 64 + w * 16;

    f32x4 acc[5];
    const f32x4 zero4 = {0.f, 0.f, 0.f, 0.f};
#pragma unroll
    for (int cf = 0; cf < 5; cf++) acc[cf] = zero4;

    for (int kt = 0; kt < 256; kt += 32) {
        short8 a = *(const short8*)(h2 + (size_t)(m0 + l15) * H_SZ + l4 * 8 + kt);
#pragma unroll
        for (int cf = 0; cf < 5; cf++) {
            short8 b = *(const short8*)(WdT + (size_t)(cf * 16 + l15) * H_SZ + l4 * 8 + kt);
            acc[cf] = __builtin_amdgcn_mfma_f32_16x16x32_bf16(a, b, acc[cf], 0, 0, 0);
        }
    }
#pragma unroll
    for (int cf = 0; cf < 5; cf++) {
        float bv = bd[cf * 16 + l15];
#pragma unroll
        for (int r = 0; r < 4; r++) acc[cf][r] += bv;
    }

#pragma unroll
    for (int r = 0; r < 4; r++) {
        const int row = m0 + l4 * 4 + r;
        float mx = acc[0][r];
#pragma unroll
        for (int cf = 1; cf < 5; cf++) mx = fmaxf(mx, acc[cf][r]);
#pragma unroll
        for (int msk = 1; msk < 16; msk <<= 1)
            mx = fmaxf(mx, __shfl_xor(mx, msk, 64));
        float s = 0.f;
#pragma unroll
        for (int cf = 0; cf < 5; cf++) s += __expf(acc[cf][r] - mx);
#pragma unroll
        for (int msk = 1; msk < 16; msk <<= 1)
            s += __shfl_xor(s, msk, 64);
        const int lab = labels[row];
        float pl = 0.f;
#pragma unroll
        for (int cf = 0; cf < 5; cf++)
            pl += (cf * 16 + l15 == lab) ? acc[cf][r] : 0.f;
#pragma unroll
        for (int msk = 1; msk < 16; msk <<= 1)
            pl += __shfl_xor(pl, msk, 64);
        if (l15 == 0)
            atomicAdd(out, (logf(s) + mx - pl) * (1.0f / B_SZ));
    }
}

extern "C" void kernel_launch(void* const* d_in, const int* in_sizes, int n_in,
                              void* d_out, int out_size, void* d_ws, size_t ws_size,
                              hipStream_t stream) {
    const int*   features = (const int*)d_in[0];
    const int*   labels   = (const int*)d_in[1];
    const float* emb      = (const float*)d_in[2];
    const float* W1       = (const float*)d_in[3];
    const float* b1       = (const float*)d_in[4];
    const float* W2       = (const float*)d_in[5];
    const float* b2       = (const float*)d_in[6];
    const float* Wd       = (const float*)d_in[7];
    const float* bd       = (const float*)d_in[8];
    float* out = (float*)d_out;

    char* base = (char*)d_ws;
    float*  G1v = (float*)base;      base += (size_t)V_SZ * G4 * 4;            // 320 KB
    ushort* W1f = (ushort*)base;     base += (size_t)8 * 8 * 8 * 512 * 2;      // 512 KB
    ushort* W2f = (ushort*)base;     base += (size_t)8 * 16 * 8 * 512 * 2;     // 1 MB
    ushort* WdT = (ushort*)base;     base += (size_t)V_SZ * H_SZ * 2;          // 40 KB
    ushort* h2g = (ushort*)base;     base += (size_t)B_SZ * H_SZ * 2;          // 2 MB

    (void)hipMemsetAsync(d_out, 0, sizeof(float), stream);
    g1_kernel<<<(V_SZ * G4 + 255) / 256, 256, 0, stream>>>(emb, W1, b1, G1v);
    wtransf2<<<(8 * 8 * 8 * 512) / 256, 256, 0, stream>>>(W1, E_SZ, 7, 3, W1f);
    wtransf2<<<(8 * 16 * 8 * 512) / 256, 256, 0, stream>>>(W2, 0, 15, 4, W2f);
    wdtrans<<<(V_SZ * H_SZ + 255) / 256, 256, 0, stream>>>(Wd, WdT);

    lstm_rowlocal<<<NBLK, 512, 0, stream>>>(features, G1v, b2, W1f, W2f, h2g, 0);

    dense_loss<<<B_SZ / 64, 256, 0, stream>>>(h2g, WdT, bd, labels, out);
}